// Round 2
// baseline (1802.939 us; speedup 1.0000x reference)
//
#include <hip/hip_runtime.h>
#include <cmath>
#include <cstdint>

namespace {

constexpr int kLevels = 8;
constexpr uint32_t kT = 1u << 16;
constexpr uint32_t kPrime1 = 2654435761u;
constexpr uint32_t kPrime2 = 805459861u;

struct LevelParams {
    float scale[kLevels];
    uint32_t res[kLevels];
    uint32_t hashed_mask;
    uint32_t used0;   // level-0 LDS entries
    uint32_t used1;   // level-1 LDS entries
    uint32_t off1;    // level-1 entry offset in LDS
};

__device__ __forceinline__ uint32_t pack_bf16x2(float2 v) {
    uint32_t a = __float_as_uint(v.x), b = __float_as_uint(v.y);
    a = (a + 0x7FFFu + ((a >> 16) & 1u)) >> 16;   // RNE to bf16
    b = (b + 0x7FFFu + ((b >> 16) & 1u)) >> 16;
    return a | (b << 16);
}

__global__ __launch_bounds__(1024) void ngp_mask_kernel(
    const float* __restrict__ uvi,
    const float* __restrict__ table,
    const float* __restrict__ W1,
    const float* __restrict__ b1,
    const float* __restrict__ W2,
    const float* __restrict__ b2,
    float* __restrict__ out,
    int n, LevelParams lp)
{
    extern __shared__ uint32_t lds[];
    const float2* __restrict__ tb = reinterpret_cast<const float2*>(table);

    // ---- stage dense levels 0,1 into LDS as packed bf16x2 ----
    for (uint32_t e = threadIdx.x; e < lp.used0; e += blockDim.x)
        lds[e] = pack_bf16x2(tb[e]);
    for (uint32_t e = threadIdx.x; e < lp.used1; e += blockDim.x)
        lds[lp.off1 + e] = pack_bf16x2(tb[kT + e]);
    __syncthreads();

    const uint32_t ppb = ((uint32_t)n + gridDim.x - 1) / gridDim.x;
    const uint32_t p_begin = blockIdx.x * ppb;
    const uint32_t p_end = min(p_begin + ppb, (uint32_t)n);

    for (uint32_t p = p_begin + threadIdx.x; p < p_end; p += blockDim.x) {
        const float ux = uvi[3 * p + 0];
        const float uy = uvi[3 * p + 1];
        const float uz = uvi[3 * p + 2];

        float enc[2 * kLevels];

        #pragma unroll
        for (int l = 0; l < kLevels; ++l) {
            const float s = lp.scale[l];
            // match jax: mul then add (no fma contraction)
            const float posx = __fadd_rn(__fmul_rn(ux, s), 0.5f);
            const float posy = __fadd_rn(__fmul_rn(uy, s), 0.5f);
            const float posz = __fadd_rn(__fmul_rn(uz, s), 0.5f);
            const float fx = floorf(posx), fy = floorf(posy), fz = floorf(posz);
            const float wx = __fsub_rn(posx, fx);
            const float wy = __fsub_rn(posy, fy);
            const float wz = __fsub_rn(posz, fz);
            const uint32_t x0 = (uint32_t)fx, y0 = (uint32_t)fy, z0 = (uint32_t)fz;

            const bool hashed = (lp.hashed_mask >> l) & 1u;

            uint32_t hx0, hx1, hy0, hy1, hz0, hz1;
            if (hashed) {
                hx0 = x0;             hx1 = x0 + 1u;
                hy0 = y0 * kPrime1;   hy1 = hy0 + kPrime1;
                hz0 = z0 * kPrime2;   hz1 = hz0 + kPrime2;
            } else {
                const uint32_t r  = lp.res[l];
                const uint32_t r2 = r * r;
                hx0 = x0;             hx1 = x0 + 1u;
                hy0 = y0 * r;         hy1 = hy0 + r;
                hz0 = z0 * r2;        hz1 = hz0 + r2;
            }

            const float wx0 = __fsub_rn(1.f, wx);
            const float wy0 = __fsub_rn(1.f, wy);
            const float wz0 = __fsub_rn(1.f, wz);
            const float w00 = __fmul_rn(wx0, wy0);
            const float w10 = __fmul_rn(wx,  wy0);
            const float w01 = __fmul_rn(wx0, wy);
            const float w11 = __fmul_rn(wx,  wy);

            float a0 = 0.f, a1 = 0.f;

            if (l < 2) {
                // dense level from LDS (bf16x2 packed)
                const uint32_t lb = (l == 0) ? 0u : lp.off1;
                #pragma unroll
                for (int c = 0; c < 8; ++c) {
                    const uint32_t hx = (c & 1) ? hx1 : hx0;
                    const uint32_t hy = (c & 2) ? hy1 : hy0;
                    const uint32_t hz = (c & 4) ? hz1 : hz0;
                    const uint32_t idxc = hx + hy + hz;
                    const float wxy = (c & 2) ? ((c & 1) ? w11 : w01)
                                              : ((c & 1) ? w10 : w00);
                    const float wcc = __fmul_rn(wxy, (c & 4) ? wz : wz0);
                    const uint32_t wv = lds[lb + idxc];
                    const float t0 = __uint_as_float(wv << 16);
                    const float t1 = __uint_as_float(wv & 0xFFFF0000u);
                    a0 = __fadd_rn(a0, __fmul_rn(t0, wcc));
                    a1 = __fadd_rn(a1, __fmul_rn(t1, wcc));
                }
            } else {
                const uint32_t base = (uint32_t)l << 16;
                #pragma unroll
                for (int c = 0; c < 8; ++c) {
                    const uint32_t hx = (c & 1) ? hx1 : hx0;
                    const uint32_t hy = (c & 2) ? hy1 : hy0;
                    const uint32_t hz = (c & 4) ? hz1 : hz0;
                    const uint32_t idxc = (hx ^ hy ^ hz) & (kT - 1u);
                    const float wxy = (c & 2) ? ((c & 1) ? w11 : w01)
                                              : ((c & 1) ? w10 : w00);
                    const float wcc = __fmul_rn(wxy, (c & 4) ? wz : wz0);
                    const float2 t = tb[base + idxc];
                    a0 = __fadd_rn(a0, __fmul_rn(t.x, wcc));
                    a1 = __fadd_rn(a1, __fmul_rn(t.y, wcc));
                }
            }
            enc[2 * l + 0] = a0;
            enc[2 * l + 1] = a1;
        }

        // MLP: h = relu(enc @ W1 + b1); logit = h @ W2 + b2; sigmoid
        float logit = b2[0];
        #pragma unroll
        for (int j = 0; j < 64; ++j) {
            float h = b1[j];
            #pragma unroll
            for (int k = 0; k < 16; ++k)
                h = fmaf(enc[k], W1[k * 64 + j], h);
            h = fmaxf(h, 0.f);
            logit = fmaf(h, W2[j], logit);
        }

        out[p] = 1.f / (1.f + __expf(-logit));
    }
}

} // namespace

extern "C" void kernel_launch(void* const* d_in, const int* in_sizes, int n_in,
                              void* d_out, int out_size, void* d_ws, size_t ws_size,
                              hipStream_t stream)
{
    const float* uvi   = (const float*)d_in[0];
    const float* table = (const float*)d_in[1];
    const float* W1    = (const float*)d_in[2];
    const float* b1    = (const float*)d_in[3];
    const float* W2    = (const float*)d_in[4];
    const float* b2    = (const float*)d_in[5];
    float* out = (float*)d_out;

    const int n = in_sizes[0] / 3;

    // Replicate numpy's double-precision level math exactly.
    LevelParams lp;
    const double B = exp(log(2048.0 / 16.0) / (double)(kLevels - 1));
    uint32_t mask = 0;
    for (int l = 0; l < kLevels; ++l) {
        const double scale_d = 16.0 * pow(B, (double)l) - 1.0;
        const long long res = (long long)ceil(scale_d) + 1;
        lp.scale[l] = (float)scale_d;
        lp.res[l]   = (uint32_t)res;
        if (res * res * res > (long long)kT) mask |= (1u << l);
    }
    lp.hashed_mask = mask;

    // Dense-level LDS footprints: max index = res*(1 + res + res^2)
    const uint32_t r0 = lp.res[0], r1 = lp.res[1];
    lp.used0 = r0 * (1u + r0 + r0 * r0) + 1u;
    lp.used1 = r1 * (1u + r1 + r1 * r1) + 1u;
    lp.off1  = lp.used0;
    const size_t ldsBytes = (size_t)(lp.used0 + lp.used1) * 4u;

    static_assert(sizeof(LevelParams) <= 128, "param size");
    hipFuncSetAttribute(reinterpret_cast<const void*>(ngp_mask_kernel),
                        hipFuncAttributeMaxDynamicSharedMemorySize,
                        (int)ldsBytes);

    dim3 block(1024);
    dim3 grid(256);
    hipLaunchKernelGGL(ngp_mask_kernel, grid, block, ldsBytes, stream,
                       uvi, table, W1, b1, W2, b2, out, n, lp);
}

// Round 3
// 1764.944 us; speedup vs baseline: 1.0215x; 1.0215x over previous
//
#include <hip/hip_runtime.h>
#include <cmath>
#include <cstdint>

namespace {

constexpr int kLevels = 8;
constexpr uint32_t kT = 1u << 16;
constexpr uint32_t kPrime1 = 2654435761u;
constexpr uint32_t kPrime2 = 805459861u;

struct LevelParams {
    float scale[kLevels];
    uint32_t res[kLevels];
    uint32_t hashed_mask;
    uint32_t used0;   // level-0 LDS entries
    uint32_t used1;   // level-1 LDS entries
    uint32_t off1;    // level-1 entry offset in LDS
};

__device__ __forceinline__ uint32_t pack_bf16x2(float2 v) {
    uint32_t a = __float_as_uint(v.x), b = __float_as_uint(v.y);
    a = (a + 0x7FFFu + ((a >> 16) & 1u)) >> 16;   // RNE to bf16
    b = (b + 0x7FFFu + ((b >> 16) & 1u)) >> 16;
    return a | (b << 16);
}

// block = 1024 threads (16 waves). min 4 waves/EU -> VGPR cap 128 (kernel
// wants ~92): NO spills. 149 KB LDS -> exactly 1 WG/CU, 16 waves/CU.
__global__ __launch_bounds__(1024, 4) void ngp_mask_kernel(
    const float* __restrict__ uvi,
    const float* __restrict__ table,
    const float* __restrict__ W1,
    const float* __restrict__ b1,
    const float* __restrict__ W2,
    const float* __restrict__ b2,
    float* __restrict__ out,
    int n, LevelParams lp)
{
    extern __shared__ uint32_t lds[];
    const float2* __restrict__ tb = reinterpret_cast<const float2*>(table);

    // ---- stage dense levels 0,1 into LDS as packed bf16x2 ----
    for (uint32_t e = threadIdx.x; e < lp.used0; e += blockDim.x)
        lds[e] = pack_bf16x2(tb[e]);
    for (uint32_t e = threadIdx.x; e < lp.used1; e += blockDim.x)
        lds[lp.off1 + e] = pack_bf16x2(tb[kT + e]);
    __syncthreads();

    const uint32_t ppb = ((uint32_t)n + gridDim.x - 1) / gridDim.x;
    const uint32_t p_begin = blockIdx.x * ppb;
    const uint32_t p_end = min(p_begin + ppb, (uint32_t)n);

    for (uint32_t p = p_begin + threadIdx.x; p < p_end; p += blockDim.x) {
        const float ux = uvi[3 * p + 0];
        const float uy = uvi[3 * p + 1];
        const float uz = uvi[3 * p + 2];

        float enc[2 * kLevels];

        #pragma unroll
        for (int l = 0; l < kLevels; ++l) {
            const float s = lp.scale[l];
            // match jax: mul then add (no fma contraction)
            const float posx = __fadd_rn(__fmul_rn(ux, s), 0.5f);
            const float posy = __fadd_rn(__fmul_rn(uy, s), 0.5f);
            const float posz = __fadd_rn(__fmul_rn(uz, s), 0.5f);
            const float fx = floorf(posx), fy = floorf(posy), fz = floorf(posz);
            const float wx = __fsub_rn(posx, fx);
            const float wy = __fsub_rn(posy, fy);
            const float wz = __fsub_rn(posz, fz);
            const uint32_t x0 = (uint32_t)fx, y0 = (uint32_t)fy, z0 = (uint32_t)fz;

            const bool hashed = (lp.hashed_mask >> l) & 1u;

            uint32_t hx0, hx1, hy0, hy1, hz0, hz1;
            if (hashed) {
                hx0 = x0;             hx1 = x0 + 1u;
                hy0 = y0 * kPrime1;   hy1 = hy0 + kPrime1;
                hz0 = z0 * kPrime2;   hz1 = hz0 + kPrime2;
            } else {
                const uint32_t r  = lp.res[l];
                const uint32_t r2 = r * r;
                hx0 = x0;             hx1 = x0 + 1u;
                hy0 = y0 * r;         hy1 = hy0 + r;
                hz0 = z0 * r2;        hz1 = hz0 + r2;
            }

            const float wx0 = __fsub_rn(1.f, wx);
            const float wy0 = __fsub_rn(1.f, wy);
            const float wz0 = __fsub_rn(1.f, wz);
            const float w00 = __fmul_rn(wx0, wy0);
            const float w10 = __fmul_rn(wx,  wy0);
            const float w01 = __fmul_rn(wx0, wy);
            const float w11 = __fmul_rn(wx,  wy);

            float a0 = 0.f, a1 = 0.f;

            if (l < 2) {
                // dense level from LDS (bf16x2 packed)
                const uint32_t lb = (l == 0) ? 0u : lp.off1;
                #pragma unroll
                for (int c = 0; c < 8; ++c) {
                    const uint32_t hx = (c & 1) ? hx1 : hx0;
                    const uint32_t hy = (c & 2) ? hy1 : hy0;
                    const uint32_t hz = (c & 4) ? hz1 : hz0;
                    const uint32_t idxc = hx + hy + hz;
                    const float wxy = (c & 2) ? ((c & 1) ? w11 : w01)
                                              : ((c & 1) ? w10 : w00);
                    const float wcc = __fmul_rn(wxy, (c & 4) ? wz : wz0);
                    const uint32_t wv = lds[lb + idxc];
                    const float t0 = __uint_as_float(wv << 16);
                    const float t1 = __uint_as_float(wv & 0xFFFF0000u);
                    a0 = __fadd_rn(a0, __fmul_rn(t0, wcc));
                    a1 = __fadd_rn(a1, __fmul_rn(t1, wcc));
                }
            } else {
                const uint32_t base = (uint32_t)l << 16;
                #pragma unroll
                for (int c = 0; c < 8; ++c) {
                    const uint32_t hx = (c & 1) ? hx1 : hx0;
                    const uint32_t hy = (c & 2) ? hy1 : hy0;
                    const uint32_t hz = (c & 4) ? hz1 : hz0;
                    const uint32_t idxc = (hx ^ hy ^ hz) & (kT - 1u);
                    const float wxy = (c & 2) ? ((c & 1) ? w11 : w01)
                                              : ((c & 1) ? w10 : w00);
                    const float wcc = __fmul_rn(wxy, (c & 4) ? wz : wz0);
                    const float2 t = tb[base + idxc];
                    a0 = __fadd_rn(a0, __fmul_rn(t.x, wcc));
                    a1 = __fadd_rn(a1, __fmul_rn(t.y, wcc));
                }
            }
            enc[2 * l + 0] = a0;
            enc[2 * l + 1] = a1;
        }

        // MLP: h = relu(enc @ W1 + b1); logit = h @ W2 + b2; sigmoid
        float logit = b2[0];
        #pragma unroll
        for (int j = 0; j < 64; ++j) {
            float h = b1[j];
            #pragma unroll
            for (int k = 0; k < 16; ++k)
                h = fmaf(enc[k], W1[k * 64 + j], h);
            h = fmaxf(h, 0.f);
            logit = fmaf(h, W2[j], logit);
        }

        out[p] = 1.f / (1.f + __expf(-logit));
    }
}

} // namespace

extern "C" void kernel_launch(void* const* d_in, const int* in_sizes, int n_in,
                              void* d_out, int out_size, void* d_ws, size_t ws_size,
                              hipStream_t stream)
{
    const float* uvi   = (const float*)d_in[0];
    const float* table = (const float*)d_in[1];
    const float* W1    = (const float*)d_in[2];
    const float* b1    = (const float*)d_in[3];
    const float* W2    = (const float*)d_in[4];
    const float* b2    = (const float*)d_in[5];
    float* out = (float*)d_out;

    const int n = in_sizes[0] / 3;

    // Replicate numpy's double-precision level math exactly.
    LevelParams lp;
    const double B = exp(log(2048.0 / 16.0) / (double)(kLevels - 1));
    uint32_t mask = 0;
    for (int l = 0; l < kLevels; ++l) {
        const double scale_d = 16.0 * pow(B, (double)l) - 1.0;
        const long long res = (long long)ceil(scale_d) + 1;
        lp.scale[l] = (float)scale_d;
        lp.res[l]   = (uint32_t)res;
        if (res * res * res > (long long)kT) mask |= (1u << l);
    }
    lp.hashed_mask = mask;

    // Dense-level LDS footprints: max index = res*(1 + res + res^2)
    const uint32_t r0 = lp.res[0], r1 = lp.res[1];
    lp.used0 = r0 * (1u + r0 + r0 * r0) + 1u;
    lp.used1 = r1 * (1u + r1 + r1 * r1) + 1u;
    lp.off1  = lp.used0;
    const size_t ldsBytes = (size_t)(lp.used0 + lp.used1) * 4u;

    static_assert(sizeof(LevelParams) <= 128, "param size");
    hipFuncSetAttribute(reinterpret_cast<const void*>(ngp_mask_kernel),
                        hipFuncAttributeMaxDynamicSharedMemorySize,
                        (int)ldsBytes);

    dim3 block(1024);
    dim3 grid(256);
    hipLaunchKernelGGL(ngp_mask_kernel, grid, block, ldsBytes, stream,
                       uvi, table, W1, b1, W2, b2, out, n, lp);
}

// Round 4
// 599.050 us; speedup vs baseline: 3.0097x; 2.9462x over previous
//
#include <hip/hip_runtime.h>
#include <cmath>
#include <cstdint>

namespace {

constexpr int kLevels = 8;
constexpr uint32_t kT = 1u << 16;
constexpr uint32_t kPrime1 = 2654435761u;
constexpr uint32_t kPrime2 = 805459861u;

struct LevelParams {
    float scale[kLevels];
    uint32_t res[kLevels];
    uint32_t hashed_mask;
};

// ---------------- Kernel A: hash-grid encode only (gather-heavy) ----------
// No MLP -> low VGPR -> high occupancy -> many outstanding gathers.
// enc written as packed bf16 pairs (truncation; |err| ~0.4% rel of ~1e-4
// values -> ~1e-6 at the output, threshold is 1e-2).
__global__ void ngp_encode_kernel(
    const float* __restrict__ uvi,
    const float* __restrict__ table,
    uint32_t* __restrict__ enc_out,   // [n][8] u32 (bf16x2 per level)
    int n, LevelParams lp)
{
    const int i = blockIdx.x * blockDim.x + threadIdx.x;
    if (i >= n) return;

    const float ux = uvi[3 * i + 0];
    const float uy = uvi[3 * i + 1];
    const float uz = uvi[3 * i + 2];

    const float2* __restrict__ tb = reinterpret_cast<const float2*>(table);

    uint32_t packed[kLevels];

    #pragma unroll
    for (int l = 0; l < kLevels; ++l) {
        const float s = lp.scale[l];
        const float px = fmaf(ux, s, 0.5f);
        const float py = fmaf(uy, s, 0.5f);
        const float pz = fmaf(uz, s, 0.5f);
        const float fx = floorf(px), fy = floorf(py), fz = floorf(pz);
        const float wx = px - fx, wy = py - fy, wz = pz - fz;
        const uint32_t x0 = (uint32_t)fx, y0 = (uint32_t)fy, z0 = (uint32_t)fz;

        const bool hashed = (lp.hashed_mask >> l) & 1u;

        uint32_t hx0, hx1, hy0, hy1, hz0, hz1;
        if (hashed) {
            hx0 = x0;             hx1 = x0 + 1u;
            hy0 = y0 * kPrime1;   hy1 = hy0 + kPrime1;
            hz0 = z0 * kPrime2;   hz1 = hz0 + kPrime2;
        } else {
            const uint32_t r  = lp.res[l];
            const uint32_t r2 = r * r;
            hx0 = x0;             hx1 = x0 + 1u;
            hy0 = y0 * r;         hy1 = hy0 + r;
            hz0 = z0 * r2;        hz1 = hz0 + r2;
        }

        const float wx0 = 1.f - wx, wy0 = 1.f - wy, wz0 = 1.f - wz;
        const float w00 = wx0 * wy0;
        const float w10 = wx  * wy0;
        const float w01 = wx0 * wy;
        const float w11 = wx  * wy;

        const uint32_t base = (uint32_t)l << 16;
        float a0 = 0.f, a1 = 0.f;

        #pragma unroll
        for (int c = 0; c < 8; ++c) {
            const uint32_t hx = (c & 1) ? hx1 : hx0;
            const uint32_t hy = (c & 2) ? hy1 : hy0;
            const uint32_t hz = (c & 4) ? hz1 : hz0;
            uint32_t idxc;
            if (hashed) idxc = (hx ^ hy ^ hz) & (kT - 1u);
            else        idxc = hx + hy + hz;
            const float wxy = (c & 2) ? ((c & 1) ? w11 : w01)
                                      : ((c & 1) ? w10 : w00);
            const float wcc = wxy * ((c & 4) ? wz : wz0);
            const float2 t = tb[base + idxc];
            a0 = fmaf(t.x, wcc, a0);
            a1 = fmaf(t.y, wcc, a1);
        }
        // truncate-to-bf16 pack: feature0 in low half, feature1 in high half
        packed[l] = (__float_as_uint(a0) >> 16) |
                    (__float_as_uint(a1) & 0xFFFF0000u);
    }

    uint4* __restrict__ eo = reinterpret_cast<uint4*>(enc_out);
    eo[2 * i + 0] = make_uint4(packed[0], packed[1], packed[2], packed[3]);
    eo[2 * i + 1] = make_uint4(packed[4], packed[5], packed[6], packed[7]);
}

// ---------------- Kernel B: tiny MLP (VALU-bound, streams enc) ------------
__global__ void ngp_mlp_kernel(
    const uint32_t* __restrict__ enc_in,
    const float* __restrict__ W1,
    const float* __restrict__ b1,
    const float* __restrict__ W2,
    const float* __restrict__ b2,
    float* __restrict__ out, int n)
{
    const int i = blockIdx.x * blockDim.x + threadIdx.x;
    if (i >= n) return;

    const uint4* __restrict__ ei = reinterpret_cast<const uint4*>(enc_in);
    const uint4 e0 = ei[2 * i + 0];
    const uint4 e1 = ei[2 * i + 1];
    const uint32_t pw[8] = {e0.x, e0.y, e0.z, e0.w, e1.x, e1.y, e1.z, e1.w};

    float enc[16];
    #pragma unroll
    for (int l = 0; l < 8; ++l) {
        enc[2 * l + 0] = __uint_as_float(pw[l] << 16);
        enc[2 * l + 1] = __uint_as_float(pw[l] & 0xFFFF0000u);
    }

    // W1/b1/W2 at compile-time indices -> uniform scalar loads.
    float logit = b2[0];
    #pragma unroll
    for (int j = 0; j < 64; ++j) {
        float h = b1[j];
        #pragma unroll
        for (int k = 0; k < 16; ++k)
            h = fmaf(enc[k], W1[k * 64 + j], h);
        h = fmaxf(h, 0.f);
        logit = fmaf(h, W2[j], logit);
    }

    out[i] = 1.f / (1.f + __expf(-logit));
}

// ---------------- Fallback: round-1 fused kernel (if ws too small) --------
__global__ __launch_bounds__(256) void ngp_fused_kernel(
    const float* __restrict__ uvi,
    const float* __restrict__ table,
    const float* __restrict__ W1,
    const float* __restrict__ b1,
    const float* __restrict__ W2,
    const float* __restrict__ b2,
    float* __restrict__ out,
    int n, LevelParams lp)
{
    const int i = blockIdx.x * blockDim.x + threadIdx.x;
    if (i >= n) return;

    const float ux = uvi[3 * i + 0];
    const float uy = uvi[3 * i + 1];
    const float uz = uvi[3 * i + 2];
    const float2* __restrict__ tb = reinterpret_cast<const float2*>(table);

    float enc[2 * kLevels];
    #pragma unroll
    for (int l = 0; l < kLevels; ++l) {
        const float s = lp.scale[l];
        const float px = fmaf(ux, s, 0.5f);
        const float py = fmaf(uy, s, 0.5f);
        const float pz = fmaf(uz, s, 0.5f);
        const float fx = floorf(px), fy = floorf(py), fz = floorf(pz);
        const float wx = px - fx, wy = py - fy, wz = pz - fz;
        const uint32_t x0 = (uint32_t)fx, y0 = (uint32_t)fy, z0 = (uint32_t)fz;
        const bool hashed = (lp.hashed_mask >> l) & 1u;
        uint32_t hx0, hx1, hy0, hy1, hz0, hz1;
        if (hashed) {
            hx0 = x0;             hx1 = x0 + 1u;
            hy0 = y0 * kPrime1;   hy1 = hy0 + kPrime1;
            hz0 = z0 * kPrime2;   hz1 = hz0 + kPrime2;
        } else {
            const uint32_t r  = lp.res[l];
            const uint32_t r2 = r * r;
            hx0 = x0;             hx1 = x0 + 1u;
            hy0 = y0 * r;         hy1 = hy0 + r;
            hz0 = z0 * r2;        hz1 = hz0 + r2;
        }
        const float wx0 = 1.f - wx, wy0 = 1.f - wy, wz0 = 1.f - wz;
        const float w00 = wx0 * wy0, w10 = wx * wy0, w01 = wx0 * wy, w11 = wx * wy;
        const uint32_t base = (uint32_t)l << 16;
        float a0 = 0.f, a1 = 0.f;
        #pragma unroll
        for (int c = 0; c < 8; ++c) {
            const uint32_t hx = (c & 1) ? hx1 : hx0;
            const uint32_t hy = (c & 2) ? hy1 : hy0;
            const uint32_t hz = (c & 4) ? hz1 : hz0;
            uint32_t idxc;
            if (hashed) idxc = (hx ^ hy ^ hz) & (kT - 1u);
            else        idxc = hx + hy + hz;
            const float wxy = (c & 2) ? ((c & 1) ? w11 : w01)
                                      : ((c & 1) ? w10 : w00);
            const float wcc = wxy * ((c & 4) ? wz : wz0);
            const float2 t = tb[base + idxc];
            a0 = fmaf(t.x, wcc, a0);
            a1 = fmaf(t.y, wcc, a1);
        }
        enc[2 * l + 0] = a0;
        enc[2 * l + 1] = a1;
    }
    float logit = b2[0];
    #pragma unroll
    for (int j = 0; j < 64; ++j) {
        float h = b1[j];
        #pragma unroll
        for (int k = 0; k < 16; ++k)
            h = fmaf(enc[k], W1[k * 64 + j], h);
        h = fmaxf(h, 0.f);
        logit = fmaf(h, W2[j], logit);
    }
    out[i] = 1.f / (1.f + __expf(-logit));
}

} // namespace

extern "C" void kernel_launch(void* const* d_in, const int* in_sizes, int n_in,
                              void* d_out, int out_size, void* d_ws, size_t ws_size,
                              hipStream_t stream)
{
    const float* uvi   = (const float*)d_in[0];
    const float* table = (const float*)d_in[1];
    const float* W1    = (const float*)d_in[2];
    const float* b1    = (const float*)d_in[3];
    const float* W2    = (const float*)d_in[4];
    const float* b2    = (const float*)d_in[5];
    float* out = (float*)d_out;

    const int n = in_sizes[0] / 3;

    // Replicate numpy's double-precision level math exactly.
    LevelParams lp;
    const double B = exp(log(2048.0 / 16.0) / (double)(kLevels - 1));
    uint32_t mask = 0;
    for (int l = 0; l < kLevels; ++l) {
        const double scale_d = 16.0 * pow(B, (double)l) - 1.0;
        const long long res = (long long)ceil(scale_d) + 1;
        lp.scale[l] = (float)scale_d;
        lp.res[l]   = (uint32_t)res;
        if (res * res * res > (long long)kT) mask |= (1u << l);
    }
    lp.hashed_mask = mask;

    const size_t enc_bytes = (size_t)n * 8u * 4u;   // [n][8] u32

    dim3 block(256);
    dim3 grid((unsigned)((n + 255) / 256));

    if (ws_size >= enc_bytes) {
        uint32_t* enc = (uint32_t*)d_ws;
        hipLaunchKernelGGL(ngp_encode_kernel, grid, block, 0, stream,
                           uvi, table, enc, n, lp);
        hipLaunchKernelGGL(ngp_mlp_kernel, grid, block, 0, stream,
                           enc, W1, b1, W2, b2, out, n);
    } else {
        hipLaunchKernelGGL(ngp_fused_kernel, grid, block, 0, stream,
                           uvi, table, W1, b1, W2, b2, out, n, lp);
    }
}